// Round 1
// baseline (100.068 us; speedup 1.0000x reference)
//
#include <hip/hip_runtime.h>

#define S   500
#define B   32
#define T   40
#define L   20
#define NT  10000
#define NEG (-1e9f)
#define INV_LN2 1.44269504088896340736f
#define LN2f    0.69314718055994530942f

// Kernel 1: em[t,b,s] = sum_l logE[s, stories[b,t,l]] (+ priors[s] at t=0)
// Two states per block; rows stored INTERLEAVED in LDS as float2 so each
// token gather is one ds_read_b64. Staging is float4-vectorized: 2 global
// dwordx4 loads + 2 ds_write_b128 per 4 tokens (was 8 loads + 4 ds_write_b64).
__global__ __launch_bounds__(512) void emission_kernel(
    const float* __restrict__ logE, const int* __restrict__ stories,
    const float* __restrict__ priors, float* __restrict__ out)
{
    __shared__ float2 pair[NT];          // pair[tok] = {row_s0[tok], row_s1[tok]}
    const int s0  = blockIdx.x * 2;      // 250 blocks -> states {s0, s0+1}
    const int tid = threadIdx.x;

    // rows are 40000 B apart -> 16B-aligned, float4 OK
    const float4* r0 = (const float4*)(logE + (size_t)s0 * NT);
    const float4* r1 = (const float4*)(logE + (size_t)(s0 + 1) * NT);
    for (int i = tid; i < NT / 4; i += 512) {
        const float4 a4 = r0[i], b4 = r1[i];
        float2* dst = pair + i * 4;      // 32 contiguous bytes -> 2x ds_write_b128
        dst[0] = make_float2(a4.x, b4.x);
        dst[1] = make_float2(a4.y, b4.y);
        dst[2] = make_float2(a4.z, b4.z);
        dst[3] = make_float2(a4.w, b4.w);
    }
    __syncthreads();

    const float p0 = priors[s0], p1 = priors[s0 + 1];
    for (int p = tid; p < B * T; p += 512) {            // p = b*T + t
        const int4* tk = (const int4*)(stories + p * L);  // 80B-aligned
        float acc0 = 0.f, acc1 = 0.f;
        #pragma unroll
        for (int q = 0; q < L / 4; ++q) {
            const int4 v = tk[q];
            float2 a = pair[v.x], b2 = pair[v.y], c = pair[v.z], d = pair[v.w];
            acc0 += a.x + b2.x + c.x + d.x;
            acc1 += a.y + b2.y + c.y + d.y;
        }
        const int b = p / T, t = p % T;
        if (t == 0) { acc0 += p0; acc1 += p1; }
        *(float2*)(out + ((size_t)t * B + b) * S + s0) = make_float2(acc0, acc1);
    }
}

// Kernel 2: forward recursion, one block per batch element b.
// Key change vs previous version: the per-iteration barrier is a raw
// s_barrier guarded ONLY by lgkmcnt(0) (the LDS alpha exchange), so the em
// prefetch (global load, 2-deep) and the alpha store stay in flight across
// iterations instead of being drained by __syncthreads' vmcnt(0).
// Recursion runs in base-2 domain (alpha' = alpha/ln2): exp2/log2 need no
// scale muls; output store multiplies back by ln2.
__global__ __launch_bounds__(512) void forward_kernel(
    const float* __restrict__ logT, float* __restrict__ out)
{
    constexpr int PAD = 16, AN = 768;    // front pad 16, back pad >= 200
    __shared__ float abuf[2][AN];
    const int s = threadIdx.x;
    const int b = blockIdx.x;
    const bool act = (s < S);
    const int i = s + PAD;

    // init pads (and everything) to finite zeros — LDS is undefined at entry
    for (int k = s; k < AN; k += 512) { abuf[0][k] = 0.f; abuf[1][k] = 0.f; }

    float tv0 = NEG, tv1 = NEG, tv2 = NEG, tv3 = NEG, tv4 = NEG, tv5 = NEG, tv6 = NEG;
    if (act) {
        const int x = s % 10, y = (s / 10) % 10, z = s / 100;
        const float* rowT = logT + (size_t)s * S;
        tv0 = rowT[s];
        if (x + 1 < 10) tv1 = rowT[s + 1];
        if (x - 1 >= 0) tv2 = rowT[s - 1];
        if (y + 1 < 10) tv3 = rowT[s + 10];
        if (y - 1 >= 0) tv4 = rowT[s - 10];
        if (z + 1 < 5)  tv5 = rowT[s + 100];
        if (z + 2 < 5)  tv6 = rowT[s + 200];
    }
    // base-2 domain (NEG*1.44e0 stays finite; exp2(v-m) still flushes to 0)
    tv0 *= INV_LN2; tv1 *= INV_LN2; tv2 *= INV_LN2; tv3 *= INV_LN2;
    tv4 *= INV_LN2; tv5 *= INV_LN2; tv6 *= INV_LN2;

    const size_t base = (size_t)b * S + s;
    float self = 0.f;                       // alpha'[t-1][s] register copy (scaled)
    if (act) self = out[base] * INV_LN2;    // em[0] already includes prior
    abuf[0][i] = self;

    float em1 = 0.f, em2 = 0.f;             // 2-deep em prefetch (natural log)
    if (act) em1 = out[(size_t)B * S + base];
    if (act) em2 = out[(size_t)2 * B * S + base];

    __asm__ __volatile__("s_waitcnt lgkmcnt(0)" ::: "memory");
    __builtin_amdgcn_s_barrier();
    __asm__ __volatile__("" ::: "memory");

    const float* ap = abuf[0];
    float*       an = abuf[1];

    for (int t = 1; t < T; ++t) {
        const float em_t = em1;
        em1 = em2;
        if (act && t + 2 < T) em2 = out[(size_t)(t + 2) * B * S + base];

        float a = 0.f;
        if (act) {
            // compile-time offsets from one base -> 3x ds_read2_b32
            const float v0 = tv0 + self;
            const float v1 = tv1 + ap[i + 1];
            const float v2 = tv2 + ap[i - 1];
            const float v3 = tv3 + ap[i + 10];
            const float v4 = tv4 + ap[i - 10];
            const float v5 = tv5 + ap[i + 100];
            const float v6 = tv6 + ap[i + 200];
            // left chain folds to 3x v_max3_f32
            const float m = fmaxf(fmaxf(fmaxf(fmaxf(fmaxf(fmaxf(v0, v1), v2),
                                                    v3), v4), v5), v6);
            const float sum = exp2f(v0 - m) + exp2f(v1 - m) + exp2f(v2 - m) +
                              exp2f(v3 - m) + exp2f(v4 - m) + exp2f(v5 - m) +
                              exp2f(v6 - m);
            a = fmaf(em_t, INV_LN2, m + __log2f(sum));   // scaled alpha'
            out[(size_t)t * B * S + base] = a * LN2f;    // natural-log output
        }
        an[i] = a;
        self = a;
        float* tmp = an; an = (float*)ap; ap = tmp;   // ping-pong

        // LDS-only barrier: em prefetch + out store stay in flight (no vmcnt drain)
        __asm__ __volatile__("s_waitcnt lgkmcnt(0)" ::: "memory");
        __builtin_amdgcn_s_barrier();
        __asm__ __volatile__("" ::: "memory");
    }
}

extern "C" void kernel_launch(void* const* d_in, const int* in_sizes, int n_in,
                              void* d_out, int out_size, void* d_ws, size_t ws_size,
                              hipStream_t stream) {
    const float* priors  = (const float*)d_in[0];
    const float* logT    = (const float*)d_in[1];
    const float* logE    = (const float*)d_in[2];
    const int*   stories = (const int*)d_in[3];
    float* out = (float*)d_out;

    emission_kernel<<<S / 2, 512, 0, stream>>>(logE, stories, priors, out);
    forward_kernel<<<B, 512, 0, stream>>>(logT, out);
}